// Round 1
// baseline (210.950 us; speedup 1.0000x reference)
//
#include <hip/hip_runtime.h>

#define EMBED 128
#define NEDGES 320000
#define NNODES 10000

typedef __attribute__((ext_vector_type(4))) float f32x4;
typedef __attribute__((ext_vector_type(8))) short bf16x8;

__device__ __forceinline__ short f2bf(float f) {
  union { float f; unsigned u; } v; v.f = f;
  unsigned r = v.u + 0x7fffu + ((v.u >> 16) & 1u);
  return (short)(r >> 16);
}

// ---------------------------------------------------------------------------
// Weight conversion: fp32 [N][K] row-major -> bf16 MFMA-B fragment layout.
// Fragment element e of lane (g = lane>>4) at n covers k = 32*ks + 16*(e>>2)
// + 4*g + (e&3).  Stored as ws[((ks*4 + g)*128 + n)*8 + e].
// ---------------------------------------------------------------------------
__global__ __launch_bounds__(256) void convert_weights_kernel(
    const float* __restrict__ w1, const float* __restrict__ w2,
    short* __restrict__ w1bf, short* __restrict__ w2bf) {
  int tid = blockIdx.x * 256 + threadIdx.x;  // 0..32767
  {
    int n = tid >> 8;        // 0..127
    int k = tid & 255;       // 0..255
    int ks = k >> 5, g = (k >> 2) & 3, h = (k >> 4) & 1, j = k & 3;
    w1bf[(((ks * 4 + g) * 128 + n) << 3) + (h << 2) + j] = f2bf(w1[tid]);
  }
  if (tid < 128 * 128) {
    int n = tid >> 7;        // 0..127
    int k = tid & 127;       // 0..127
    int ks = k >> 5, g = (k >> 2) & 3, h = (k >> 4) & 1, j = k & 3;
    w2bf[(((ks * 4 + g) * 128 + n) << 3) + (h << 2) + j] = f2bf(w2[tid]);
  }
}

// ---------------------------------------------------------------------------
// Scores kernel: fused MLP  s[e] = w3 . relu(W2 . relu(W1.x + b1) + b2) + b3
// 4 waves/block, each wave computes 32 edges (2 m-tiles of 16).
// ---------------------------------------------------------------------------
__global__ __launch_bounds__(256) void scores_kernel(
    const int* __restrict__ nodes, const int* __restrict__ neigh_idx,
    const int* __restrict__ seg_ids, const float* __restrict__ u2e,
    const short* __restrict__ w1bf, const short* __restrict__ w2bf,
    const float* __restrict__ b1, const float* __restrict__ b2,
    const float* __restrict__ w3v, const float* __restrict__ b3,
    float* __restrict__ s_out) {
  // h1 staging: [wave][ks*4+g][edge (padded 32->33)][e]; pad breaks the
  // 512B gg-stride bank collision on the scalar b16 writes.
  __shared__ short h1_lds[4][16][33][8];

  const int tid = threadIdx.x;
  const int lane = tid & 63;
  const int wv = tid >> 6;
  const int g = lane >> 4;    // 0..3
  const int lm = lane & 15;   // 0..15
  const int eb = (blockIdx.x * 4 + wv) * 32;  // 10000 strips of 32 edges

  // Row pointers for this lane's two edges (m-tiles).
  const float* rowN[2];
  const float* rowU[2];
#pragma unroll
  for (int mt = 0; mt < 2; ++mt) {
    int e = eb + mt * 16 + lm;
    rowN[mt] = u2e + (size_t)neigh_idx[e] * EMBED;
    rowU[mt] = u2e + (size_t)nodes[seg_ids[e]] * EMBED;
  }

  // Gather + convert A fragments for GEMM1 (X = [e_u | u_rep], K = 256).
  // Element e of fragment ks: k = 32*ks + 16*(e>>2) + 4*g + (e&3).
  bf16x8 a1[2][8];
#pragma unroll
  for (int mt = 0; mt < 2; ++mt) {
#pragma unroll
    for (int ks = 0; ks < 8; ++ks) {
      int k0 = 32 * ks + 4 * g;  // ks<4 -> e_u row, ks>=4 -> u_rep row
      const float* src = (ks < 4) ? (rowN[mt] + k0) : (rowU[mt] + (k0 - 128));
      f32x4 lo = *(const f32x4*)src;
      f32x4 hi = *(const f32x4*)(src + 16);
      bf16x8 a;
      a[0] = f2bf(lo.x); a[1] = f2bf(lo.y); a[2] = f2bf(lo.z); a[3] = f2bf(lo.w);
      a[4] = f2bf(hi.x); a[5] = f2bf(hi.y); a[6] = f2bf(hi.z); a[7] = f2bf(hi.w);
      a1[mt][ks] = a;
    }
  }

  // GEMM1: acc[mt][nt] over K=256.
  f32x4 acc[2][8];
#pragma unroll
  for (int mt = 0; mt < 2; ++mt)
#pragma unroll
    for (int nt = 0; nt < 8; ++nt) acc[mt][nt] = (f32x4){0.f, 0.f, 0.f, 0.f};

#pragma unroll
  for (int ks = 0; ks < 8; ++ks) {
#pragma unroll
    for (int nt = 0; nt < 8; ++nt) {
      bf16x8 b = *(const bf16x8*)(w1bf + ((((4 * ks + g) * 128) + nt * 16 + lm) << 3));
      acc[0][nt] = __builtin_amdgcn_mfma_f32_16x16x32_bf16(a1[0][ks], b, acc[0][nt], 0, 0, 0);
      acc[1][nt] = __builtin_amdgcn_mfma_f32_16x16x32_bf16(a1[1][ks], b, acc[1][nt], 0, 0, 0);
    }
  }

  // Epilogue 1: relu(acc + b1) -> bf16 -> LDS in GEMM2 A-fragment layout.
  // D layout: n = 16*nt + lm (col), m = 4*g + r (row).
#pragma unroll
  for (int nt = 0; nt < 8; ++nt) {
    int n = nt * 16 + lm;
    float bias = b1[n];
    int ksg = (nt >> 1) * 4 + (lm >> 2);
    int epos = ((nt & 1) << 2) + (lm & 3);
#pragma unroll
    for (int mt = 0; mt < 2; ++mt) {
#pragma unroll
      for (int r = 0; r < 4; ++r) {
        float v = fmaxf(acc[mt][nt][r] + bias, 0.f);
        h1_lds[wv][ksg][mt * 16 + 4 * g + r][epos] = f2bf(v);
      }
    }
  }
  __syncthreads();

  // GEMM2: h2 = relu(h1 @ W2^T + b2), K=128.
  f32x4 acc2[2][8];
#pragma unroll
  for (int mt = 0; mt < 2; ++mt)
#pragma unroll
    for (int nt = 0; nt < 8; ++nt) acc2[mt][nt] = (f32x4){0.f, 0.f, 0.f, 0.f};

#pragma unroll
  for (int ks = 0; ks < 4; ++ks) {
    bf16x8 af0 = *(const bf16x8*)&h1_lds[wv][4 * ks + g][lm][0];
    bf16x8 af1 = *(const bf16x8*)&h1_lds[wv][4 * ks + g][16 + lm][0];
#pragma unroll
    for (int nt = 0; nt < 8; ++nt) {
      bf16x8 b = *(const bf16x8*)(w2bf + ((((4 * ks + g) * 128) + nt * 16 + lm) << 3));
      acc2[0][nt] = __builtin_amdgcn_mfma_f32_16x16x32_bf16(af0, b, acc2[0][nt], 0, 0, 0);
      acc2[1][nt] = __builtin_amdgcn_mfma_f32_16x16x32_bf16(af1, b, acc2[1][nt], 0, 0, 0);
    }
  }

  // Epilogue 2: relu + b2, dot with w3 (partial per lane over n), reduce
  // across the 16 lanes sharing g, add b3, store s.
  float part[2][4] = {{0.f, 0.f, 0.f, 0.f}, {0.f, 0.f, 0.f, 0.f}};
#pragma unroll
  for (int nt = 0; nt < 8; ++nt) {
    int n = nt * 16 + lm;
    float bias = b2[n];
    float w3n = w3v[n];
#pragma unroll
    for (int mt = 0; mt < 2; ++mt)
#pragma unroll
      for (int r = 0; r < 4; ++r) {
        float h2 = fmaxf(acc2[mt][nt][r] + bias, 0.f);
        part[mt][r] += h2 * w3n;
      }
  }
#pragma unroll
  for (int off = 1; off < 16; off <<= 1) {
#pragma unroll
    for (int mt = 0; mt < 2; ++mt)
#pragma unroll
      for (int r = 0; r < 4; ++r)
        part[mt][r] += __shfl_xor(part[mt][r], off, 64);
  }
  if (lm == 0) {
    float b3s = b3[0];
#pragma unroll
    for (int mt = 0; mt < 2; ++mt)
#pragma unroll
      for (int r = 0; r < 4; ++r)
        s_out[eb + mt * 16 + 4 * g + r] = part[mt][r] + b3s;
  }
}

// ---------------------------------------------------------------------------
// Segment softmax + weighted aggregation. One wave per node.
// ---------------------------------------------------------------------------
__device__ __forceinline__ int lower_bound(const int* __restrict__ a, int n, int key) {
  int lo = 0, hi = n;
  while (lo < hi) {
    int mid = (lo + hi) >> 1;
    if (a[mid] < key) lo = mid + 1; else hi = mid;
  }
  return lo;
}

__global__ __launch_bounds__(64) void agg_kernel(
    const int* __restrict__ nodes, const int* __restrict__ neigh_idx,
    const int* __restrict__ seg_ids, const float* __restrict__ u2e,
    const float* __restrict__ s, float* __restrict__ out) {
  const int node = blockIdx.x;
  const int lane = threadIdx.x;  // 0..63
  const int lo = lower_bound(seg_ids, NEDGES, node);
  const int hi = lower_bound(seg_ids, NEDGES, node + 1);
  float* orow = out + (size_t)node * EMBED;

  if (lo >= hi) {  // zero-degree fallback: u2e[nodes[node]]
    const float* src = u2e + (size_t)nodes[node] * EMBED;
    orow[lane] = src[lane];
    orow[lane + 64] = src[lane + 64];
    return;
  }

  // segment max
  float mx = -3.402823466e38f;
  for (int e = lo + lane; e < hi; e += 64) mx = fmaxf(mx, s[e]);
#pragma unroll
  for (int off = 32; off >= 1; off >>= 1) mx = fmaxf(mx, __shfl_xor(mx, off, 64));

  // segment denom
  float sum = 0.f;
  for (int e = lo + lane; e < hi; e += 64) sum += expf(s[e] - mx);
#pragma unroll
  for (int off = 32; off >= 1; off >>= 1) sum += __shfl_xor(sum, off, 64);
  float inv = 1.0f / sum;

  // weighted sum of neighbor embeddings (fp32)
  float a0 = 0.f, a1 = 0.f;
  for (int e = lo; e < hi; ++e) {
    float w = expf(s[e] - mx) * inv;  // uniform across lanes (broadcast load)
    const float* row = u2e + (size_t)neigh_idx[e] * EMBED;
    a0 += w * row[lane];
    a1 += w * row[lane + 64];
  }
  orow[lane] = a0;
  orow[lane + 64] = a1;
}

// ---------------------------------------------------------------------------
extern "C" void kernel_launch(void* const* d_in, const int* in_sizes, int n_in,
                              void* d_out, int out_size, void* d_ws, size_t ws_size,
                              hipStream_t stream) {
  const int* nodes  = (const int*)d_in[0];
  const int* neigh  = (const int*)d_in[1];
  const int* segs   = (const int*)d_in[2];
  const float* u2e  = (const float*)d_in[3];
  const float* w1   = (const float*)d_in[4];
  const float* b1   = (const float*)d_in[5];
  const float* w2   = (const float*)d_in[6];
  const float* b2   = (const float*)d_in[7];
  const float* w3   = (const float*)d_in[8];
  const float* b3   = (const float*)d_in[9];
  float* out = (float*)d_out;

  char* ws = (char*)d_ws;
  short* w1bf = (short*)ws;                       // 64 KiB
  short* w2bf = (short*)(ws + 65536);             // 32 KiB
  float* s    = (float*)(ws + 65536 + 32768);     // 1.25 MiB

  hipLaunchKernelGGL(convert_weights_kernel, dim3(128), dim3(256), 0, stream,
                     w1, w2, w1bf, w2bf);
  hipLaunchKernelGGL(scores_kernel, dim3(2500), dim3(256), 0, stream,
                     nodes, neigh, segs, u2e, w1bf, w2bf, b1, b2, w3, b3, s);
  hipLaunchKernelGGL(agg_kernel, dim3(NNODES), dim3(64), 0, stream,
                     nodes, neigh, segs, u2e, s, out);
}

// Round 5
// 200.338 us; speedup vs baseline: 1.0530x; 1.0530x over previous
//
#include <hip/hip_runtime.h>

#define EMBED 128
#define NEDGES 320000
#define NNODES 10000
#define NUSERS 100000

typedef __attribute__((ext_vector_type(4))) float f32x4;
typedef __attribute__((ext_vector_type(8))) short bf16x8;

__device__ __forceinline__ short f2bf(float f) {
  union { float f; unsigned u; } v; v.f = f;
  unsigned r = v.u + 0x7fffu + ((v.u >> 16) & 1u);
  return (short)(r >> 16);
}
__device__ __forceinline__ float bf2f(short s) {
  union { unsigned u; float f; } v;
  v.u = ((unsigned)(unsigned short)s) << 16;
  return v.f;
}

// ---------------------------------------------------------------------------
// Prep kernel (grid 1250 x 256):
//  - seg_off: off[n] = lower_bound(seg_ids, n)  (edges-parallel boundary mark)
//  - W1 -> w1a/w1b bf16 B-fragment layout; W2 -> w2bf.
// Fragment: element e of lane-group g at col n covers k = 32ks+16(e>>2)+4g+(e&3),
// stored at [((ks*4 + g)*128 + n)*8 + e].
// ---------------------------------------------------------------------------
__global__ __launch_bounds__(256) void prep_kernel(
    const int* __restrict__ seg_ids, const float* __restrict__ w1,
    const float* __restrict__ w2, int* __restrict__ off,
    short* __restrict__ w1a, short* __restrict__ w1b, short* __restrict__ w2bf) {
  int tid = blockIdx.x * 256 + threadIdx.x;
  if (tid < NEDGES) {
    int cur = seg_ids[tid];
    int prev = (tid == 0) ? -1 : seg_ids[tid - 1];
    for (int n = prev + 1; n <= cur; ++n) off[n] = tid;
    if (tid == NEDGES - 1)
      for (int n = cur + 1; n <= NNODES; ++n) off[n] = NEDGES;
  }
  if (tid < 128 * 256) {
    int n = tid >> 8, k = tid & 255;
    int kk = k & 127;
    int ks = kk >> 5, g = (kk >> 2) & 3, h = (kk >> 4) & 1, j = kk & 3;
    short* dst = (k < 128) ? w1a : w1b;
    dst[(((ks * 4 + g) * 128 + n) << 3) + (h << 2) + j] = f2bf(w1[tid]);
  }
  if (tid < 128 * 128) {
    int n = tid >> 7, kk = tid & 127;
    int ks = kk >> 5, g = (kk >> 2) & 3, h = (kk >> 4) & 1, j = kk & 3;
    w2bf[(((ks * 4 + g) * 128 + n) << 3) + (h << 2) + j] = f2bf(w2[tid]);
  }
}

// ---------------------------------------------------------------------------
// Row-GEMM: out[r] = u2e[row_idx ? row_idx[r] : r] @ W^T (+bias), K=N=128,
// output bf16 pre-swizzled into the MFMA A-fragment layout [r][ks*4+g][8].
// One wave = 32 rows.
// ---------------------------------------------------------------------------
__global__ __launch_bounds__(256) void row_gemm_kernel(
    const float* __restrict__ u2e, const int* __restrict__ row_idx,
    const short* __restrict__ wbf, const float* __restrict__ bias,
    short* __restrict__ out, int nrows) {
  const int lane = threadIdx.x & 63, wv = threadIdx.x >> 6;
  const int g = lane >> 4, lm = lane & 15;
  const int rb = (blockIdx.x * 4 + wv) * 32;
  if (rb >= nrows) return;

  bf16x8 af[2][4];
#pragma unroll
  for (int mt = 0; mt < 2; ++mt) {
    int row = rb + mt * 16 + lm;
    int rc = row < nrows ? row : nrows - 1;
    const float* src = u2e + (size_t)(row_idx ? row_idx[rc] : rc) * EMBED;
#pragma unroll
    for (int ks = 0; ks < 4; ++ks) {
      const float* p = src + 32 * ks + 4 * g;
      f32x4 lo = *(const f32x4*)p;
      f32x4 hi = *(const f32x4*)(p + 16);
      bf16x8 a;
      a[0] = f2bf(lo.x); a[1] = f2bf(lo.y); a[2] = f2bf(lo.z); a[3] = f2bf(lo.w);
      a[4] = f2bf(hi.x); a[5] = f2bf(hi.y); a[6] = f2bf(hi.z); a[7] = f2bf(hi.w);
      af[mt][ks] = a;
    }
  }

  f32x4 acc[2][8];
#pragma unroll
  for (int mt = 0; mt < 2; ++mt)
#pragma unroll
    for (int nt = 0; nt < 8; ++nt) acc[mt][nt] = (f32x4){0.f, 0.f, 0.f, 0.f};

#pragma unroll
  for (int ks = 0; ks < 4; ++ks) {
#pragma unroll
    for (int nt = 0; nt < 8; ++nt) {
      bf16x8 b = *(const bf16x8*)(wbf + ((((ks * 4 + g) * 128) + nt * 16 + lm) << 3));
      acc[0][nt] = __builtin_amdgcn_mfma_f32_16x16x32_bf16(af[0][ks], b, acc[0][nt], 0, 0, 0);
      acc[1][nt] = __builtin_amdgcn_mfma_f32_16x16x32_bf16(af[1][ks], b, acc[1][nt], 0, 0, 0);
    }
  }

  // D: col n = nt*16+lm, row m = 4g+r.  Output dim n is GEMM2's k:
  // frag = (n>>5)*4 + ((n>>2)&3), elem = ((n>>4)&1)*4 + (n&3).
#pragma unroll
  for (int nt = 0; nt < 8; ++nt) {
    float bs = bias ? bias[nt * 16 + lm] : 0.f;
    int fragoff = (((nt >> 1) * 4 + (lm >> 2)) << 3) + ((nt & 1) << 2) + (lm & 3);
#pragma unroll
    for (int mt = 0; mt < 2; ++mt)
#pragma unroll
      for (int r = 0; r < 4; ++r) {
        int u = rb + mt * 16 + 4 * g + r;
        if (u < nrows) out[(size_t)u * 128 + fragoff] = f2bf(acc[mt][nt][r] + bs);
      }
  }
}

// ---------------------------------------------------------------------------
// Scores: s[e] = w3 . relu(W2 . relu(P[neigh] + Q[seg]) + b2) + b3
// h1 fragments built directly in registers from pre-swizzled P/Q. No LDS.
// ---------------------------------------------------------------------------
__global__ __launch_bounds__(256) void scores2_kernel(
    const int* __restrict__ neigh_idx, const int* __restrict__ seg_ids,
    const short* __restrict__ P_sw, const short* __restrict__ Q_sw,
    const short* __restrict__ w2bf, const float* __restrict__ b2,
    const float* __restrict__ w3v, const float* __restrict__ b3,
    float* __restrict__ s_out) {
  const int lane = threadIdx.x & 63, wv = threadIdx.x >> 6;
  const int g = lane >> 4, lm = lane & 15;
  const int eb = (blockIdx.x * 4 + wv) * 32;

  bf16x8 h1[2][4];
#pragma unroll
  for (int mt = 0; mt < 2; ++mt) {
    int e = eb + mt * 16 + lm;
    const short* pb = P_sw + (size_t)neigh_idx[e] * 128;
    const short* qb = Q_sw + (size_t)seg_ids[e] * 128;
#pragma unroll
    for (int ks = 0; ks < 4; ++ks) {
      bf16x8 pa = *(const bf16x8*)(pb + ((ks * 4 + g) << 3));
      bf16x8 qa = *(const bf16x8*)(qb + ((ks * 4 + g) << 3));
      bf16x8 hh;
#pragma unroll
      for (int i = 0; i < 8; ++i)
        hh[i] = f2bf(fmaxf(bf2f(pa[i]) + bf2f(qa[i]), 0.f));
      h1[mt][ks] = hh;
    }
  }

  f32x4 acc2[2][8];
#pragma unroll
  for (int mt = 0; mt < 2; ++mt)
#pragma unroll
    for (int nt = 0; nt < 8; ++nt) acc2[mt][nt] = (f32x4){0.f, 0.f, 0.f, 0.f};

#pragma unroll
  for (int ks = 0; ks < 4; ++ks) {
#pragma unroll
    for (int nt = 0; nt < 8; ++nt) {
      bf16x8 b = *(const bf16x8*)(w2bf + ((((ks * 4 + g) * 128) + nt * 16 + lm) << 3));
      acc2[0][nt] = __builtin_amdgcn_mfma_f32_16x16x32_bf16(h1[0][ks], b, acc2[0][nt], 0, 0, 0);
      acc2[1][nt] = __builtin_amdgcn_mfma_f32_16x16x32_bf16(h1[1][ks], b, acc2[1][nt], 0, 0, 0);
    }
  }

  float part[2][4] = {{0.f, 0.f, 0.f, 0.f}, {0.f, 0.f, 0.f, 0.f}};
#pragma unroll
  for (int nt = 0; nt < 8; ++nt) {
    int n = nt * 16 + lm;
    float bias = b2[n];
    float w3n = w3v[n];
#pragma unroll
    for (int mt = 0; mt < 2; ++mt)
#pragma unroll
      for (int r = 0; r < 4; ++r) {
        float h2 = fmaxf(acc2[mt][nt][r] + bias, 0.f);
        part[mt][r] += h2 * w3n;
      }
  }
#pragma unroll
  for (int off = 1; off < 16; off <<= 1)
#pragma unroll
    for (int mt = 0; mt < 2; ++mt)
#pragma unroll
      for (int r = 0; r < 4; ++r)
        part[mt][r] += __shfl_xor(part[mt][r], off, 64);
  if (lm == 0) {
    float b3s = b3[0];
#pragma unroll
    for (int mt = 0; mt < 2; ++mt)
#pragma unroll
      for (int r = 0; r < 4; ++r)
        s_out[eb + mt * 16 + 4 * g + r] = part[mt][r] + b3s;
  }
}

// ---------------------------------------------------------------------------
// Softmax + weighted aggregation. One wave per node; inner loop processes
// 4 edges in parallel (16-lane groups own 32B of the embedding row).
// ---------------------------------------------------------------------------
__global__ __launch_bounds__(256) void agg2_kernel(
    const int* __restrict__ nodes, const int* __restrict__ neigh_idx,
    const float* __restrict__ u2e, const float* __restrict__ s,
    const int* __restrict__ off, float* __restrict__ out) {
  const int lane = threadIdx.x & 63, wv = threadIdx.x >> 6;
  const int node = blockIdx.x * 4 + wv;
  const int lo = off[node], hi = off[node + 1];
  float* orow = out + (size_t)node * EMBED;

  if (lo >= hi) {
    const float* src = u2e + (size_t)nodes[node] * EMBED;
    orow[lane] = src[lane];
    orow[lane + 64] = src[lane + 64];
    return;
  }

  float mx = -3.402823466e38f;
  for (int e = lo + lane; e < hi; e += 64) mx = fmaxf(mx, s[e]);
#pragma unroll
  for (int o = 32; o >= 1; o >>= 1) mx = fmaxf(mx, __shfl_xor(mx, o, 64));

  float sum = 0.f;
  for (int e = lo + lane; e < hi; e += 64) sum += expf(s[e] - mx);
#pragma unroll
  for (int o = 32; o >= 1; o >>= 1) sum += __shfl_xor(sum, o, 64);
  const float inv = 1.0f / sum;

  const int eg = lane >> 4, ld = lane & 15;
  f32x4 a0 = (f32x4){0.f, 0.f, 0.f, 0.f};
  f32x4 a1 = (f32x4){0.f, 0.f, 0.f, 0.f};
  for (int e = lo + eg; e < hi; e += 4) {
    float w = expf(s[e] - mx) * inv;
    const float* row = u2e + (size_t)neigh_idx[e] * EMBED + ld * 8;
    f32x4 r0 = *(const f32x4*)row;
    f32x4 r1 = *(const f32x4*)(row + 4);
    a0 += w * r0;
    a1 += w * r1;
  }
#pragma unroll
  for (int o = 16; o <= 32; o <<= 1) {
#pragma unroll
    for (int c = 0; c < 4; ++c) {
      a0[c] += __shfl_xor(a0[c], o, 64);
      a1[c] += __shfl_xor(a1[c], o, 64);
    }
  }
  if (eg == 0) {
    *(f32x4*)(orow + ld * 8) = a0;
    *(f32x4*)(orow + ld * 8 + 4) = a1;
  }
}

// ---------------------------------------------------------------------------
extern "C" void kernel_launch(void* const* d_in, const int* in_sizes, int n_in,
                              void* d_out, int out_size, void* d_ws, size_t ws_size,
                              hipStream_t stream) {
  const int* nodes  = (const int*)d_in[0];
  const int* neigh  = (const int*)d_in[1];
  const int* segs   = (const int*)d_in[2];
  const float* u2e  = (const float*)d_in[3];
  const float* w1   = (const float*)d_in[4];
  const float* b1   = (const float*)d_in[5];
  const float* w2   = (const float*)d_in[6];
  const float* b2   = (const float*)d_in[7];
  const float* w3   = (const float*)d_in[8];
  const float* b3   = (const float*)d_in[9];
  float* out = (float*)d_out;

  char* ws = (char*)d_ws;
  short* w1a  = (short*)(ws);                    // 32 KiB
  short* w1b  = (short*)(ws + 32768);            // 32 KiB
  short* w2bf = (short*)(ws + 65536);            // 32 KiB
  float* s    = (float*)(ws + 98304);            // 1.28 MB
  int*   off  = (int*)(ws + 1378304);            // 40 KB
  short* P_sw = (short*)(ws + 1418752);          // 25.6 MB
  short* Q_sw = (short*)(ws + 27018752);         // 2.56 MB

  hipLaunchKernelGGL(prep_kernel, dim3(1250), dim3(256), 0, stream,
                     segs, w1, w2, off, w1a, w1b, w2bf);
  hipLaunchKernelGGL(row_gemm_kernel, dim3((NUSERS + 127) / 128), dim3(256), 0, stream,
                     u2e, (const int*)nullptr, w1a, (const float*)nullptr, P_sw, NUSERS);
  hipLaunchKernelGGL(row_gemm_kernel, dim3((NNODES + 127) / 128), dim3(256), 0, stream,
                     u2e, nodes, w1b, b1, Q_sw, NNODES);
  hipLaunchKernelGGL(scores2_kernel, dim3(2500), dim3(256), 0, stream,
                     neigh, segs, P_sw, Q_sw, w2bf, b2, w3, b3, s);
  hipLaunchKernelGGL(agg2_kernel, dim3(2500), dim3(256), 0, stream,
                     nodes, neigh, u2e, s, off, out);
}

// Round 6
// 191.081 us; speedup vs baseline: 1.1040x; 1.0484x over previous
//
#include <hip/hip_runtime.h>

#define EMBED 128
#define NEDGES 320000
#define NNODES 10000
#define NUSERS 100000
#define PBLOCKS 782   // ceil(100000/128)
#define QBLOCKS 79    // ceil(10000/128)

typedef __attribute__((ext_vector_type(4))) float f32x4;
typedef __attribute__((ext_vector_type(8))) short bf16x8;

__device__ __forceinline__ short f2bf(float f) {
  union { float f; unsigned u; } v; v.f = f;
  unsigned r = v.u + 0x7fffu + ((v.u >> 16) & 1u);
  return (short)(r >> 16);
}
__device__ __forceinline__ float bf2f(short s) {
  union { unsigned u; float f; } v;
  v.u = ((unsigned)(unsigned short)s) << 16;
  return v.f;
}

// ---------------------------------------------------------------------------
// Prep kernel: seg offsets + W1/W2 -> bf16 B-fragment layout.
// Fragment: element e of lane-group g at col n covers k = 32ks+16(e>>2)+4g+(e&3),
// stored at [((ks*4+g)*128 + n)*8 + e].
// ---------------------------------------------------------------------------
__global__ __launch_bounds__(256) void prep_kernel(
    const int* __restrict__ seg_ids, const float* __restrict__ w1,
    const float* __restrict__ w2, int* __restrict__ off,
    short* __restrict__ w1a, short* __restrict__ w1b, short* __restrict__ w2bf) {
  int tid = blockIdx.x * 256 + threadIdx.x;
  if (tid < NEDGES) {
    int cur = seg_ids[tid];
    int prev = (tid == 0) ? -1 : seg_ids[tid - 1];
    for (int n = prev + 1; n <= cur; ++n) off[n] = tid;
    if (tid == NEDGES - 1)
      for (int n = cur + 1; n <= NNODES; ++n) off[n] = NEDGES;
  }
  if (tid < 128 * 256) {
    int n = tid >> 8, k = tid & 255;
    int kk = k & 127;
    int ks = kk >> 5, g = (kk >> 2) & 3, h = (kk >> 4) & 1, j = kk & 3;
    short* dst = (k < 128) ? w1a : w1b;
    dst[(((ks * 4 + g) * 128 + n) << 3) + (h << 2) + j] = f2bf(w1[tid]);
  }
  if (tid < 128 * 128) {
    int n = tid >> 7, kk = tid & 127;
    int ks = kk >> 5, g = (kk >> 2) & 3, h = (kk >> 4) & 1, j = kk & 3;
    w2bf[(((ks * 4 + g) * 128 + n) << 3) + (h << 2) + j] = f2bf(w2[tid]);
  }
}

// ---------------------------------------------------------------------------
// Merged row-GEMM (P for blocks < PBLOCKS, Q after):
//   out[r] = u2e[idx(r)] @ W^T (+bias), K=N=128, bf16 output pre-swizzled
//   into the MFMA A-fragment layout [r][ks*4+g][8].
// Epilogue stages the 32x256B wave tile in LDS (padded stride 136 shorts)
// then writes 128B/lane fully coalesced.  Wave-local lgkmcnt(0) instead of
// __syncthreads (waves may early-return -> block barrier is a hang risk).
// ---------------------------------------------------------------------------
__global__ __launch_bounds__(256) void row_gemm2_kernel(
    const float* __restrict__ u2e, const int* __restrict__ nodes,
    const short* __restrict__ w1a, const short* __restrict__ w1b,
    const float* __restrict__ b1,
    short* __restrict__ P_sw, short* __restrict__ Q_sw) {
  __shared__ short stage[4][32][136];  // 34.8 KB, +8 pad spreads banks

  const int lane = threadIdx.x & 63, wv = threadIdx.x >> 6;
  const int g = lane >> 4, lm = lane & 15;

  const bool isQ = blockIdx.x >= PBLOCKS;
  const int blk = isQ ? (int)blockIdx.x - PBLOCKS : (int)blockIdx.x;
  const int nrows = isQ ? NNODES : NUSERS;
  const short* wbf = isQ ? w1b : w1a;
  short* out = isQ ? Q_sw : P_sw;

  const int rb = (blk * 4 + wv) * 32;
  if (rb >= nrows) return;

  bf16x8 af[2][4];
#pragma unroll
  for (int mt = 0; mt < 2; ++mt) {
    int row = rb + mt * 16 + lm;
    int rc = row < nrows ? row : nrows - 1;
    const float* src = u2e + (size_t)(isQ ? nodes[rc] : rc) * EMBED;
#pragma unroll
    for (int ks = 0; ks < 4; ++ks) {
      const float* p = src + 32 * ks + 4 * g;
      f32x4 lo = *(const f32x4*)p;
      f32x4 hi = *(const f32x4*)(p + 16);
      bf16x8 a;
      a[0] = f2bf(lo.x); a[1] = f2bf(lo.y); a[2] = f2bf(lo.z); a[3] = f2bf(lo.w);
      a[4] = f2bf(hi.x); a[5] = f2bf(hi.y); a[6] = f2bf(hi.z); a[7] = f2bf(hi.w);
      af[mt][ks] = a;
    }
  }

  f32x4 acc[2][8];
#pragma unroll
  for (int mt = 0; mt < 2; ++mt)
#pragma unroll
    for (int nt = 0; nt < 8; ++nt) acc[mt][nt] = (f32x4){0.f, 0.f, 0.f, 0.f};

#pragma unroll
  for (int ks = 0; ks < 4; ++ks) {
#pragma unroll
    for (int nt = 0; nt < 8; ++nt) {
      bf16x8 b = *(const bf16x8*)(wbf + ((((ks * 4 + g) * 128) + nt * 16 + lm) << 3));
      acc[0][nt] = __builtin_amdgcn_mfma_f32_16x16x32_bf16(af[0][ks], b, acc[0][nt], 0, 0, 0);
      acc[1][nt] = __builtin_amdgcn_mfma_f32_16x16x32_bf16(af[1][ks], b, acc[1][nt], 0, 0, 0);
    }
  }

  // Epilogue: D col n = nt*16+lm, row m = 4g+r.  Output dim n is GEMM2's k:
  // fragoff = ((nt>>1)*4 + (lm>>2))*8 + (nt&1)*4 + (lm&3).
#pragma unroll
  for (int nt = 0; nt < 8; ++nt) {
    float bs = isQ ? b1[nt * 16 + lm] : 0.f;
    int fragoff = (((nt >> 1) * 4 + (lm >> 2)) << 3) + ((nt & 1) << 2) + (lm & 3);
#pragma unroll
    for (int mt = 0; mt < 2; ++mt)
#pragma unroll
      for (int r = 0; r < 4; ++r)
        stage[wv][mt * 16 + 4 * g + r][fragoff] = f2bf(acc[mt][nt][r] + bs);
  }
  // Wave-local LDS drain: same wave wrote [wv] slice, same wave reads it.
  asm volatile("s_waitcnt lgkmcnt(0)" ::: "memory");

  const int row = lane >> 1, h = lane & 1;   // 2 lanes per row, 128B each
  const int u = rb + row;
  if (u < nrows) {
    short* orow = out + (size_t)u * 128 + h * 64;
#pragma unroll
    for (int i = 0; i < 8; ++i)
      *(bf16x8*)(orow + i * 8) = *(const bf16x8*)&stage[wv][row][h * 64 + i * 8];
  }
}

// ---------------------------------------------------------------------------
// Scores: s[e] = w3 . relu(W2 . relu(P[neigh] + Q[seg]) + b2) + b3
// h1 fragments built directly in registers from pre-swizzled P/Q. No LDS.
// ---------------------------------------------------------------------------
__global__ __launch_bounds__(256) void scores2_kernel(
    const int* __restrict__ neigh_idx, const int* __restrict__ seg_ids,
    const short* __restrict__ P_sw, const short* __restrict__ Q_sw,
    const short* __restrict__ w2bf, const float* __restrict__ b2,
    const float* __restrict__ w3v, const float* __restrict__ b3,
    float* __restrict__ s_out) {
  const int lane = threadIdx.x & 63, wv = threadIdx.x >> 6;
  const int g = lane >> 4, lm = lane & 15;
  const int eb = (blockIdx.x * 4 + wv) * 32;

  bf16x8 h1[2][4];
#pragma unroll
  for (int mt = 0; mt < 2; ++mt) {
    int e = eb + mt * 16 + lm;
    const short* pb = P_sw + (size_t)neigh_idx[e] * 128;
    const short* qb = Q_sw + (size_t)seg_ids[e] * 128;
#pragma unroll
    for (int ks = 0; ks < 4; ++ks) {
      bf16x8 pa = *(const bf16x8*)(pb + ((ks * 4 + g) << 3));
      bf16x8 qa = *(const bf16x8*)(qb + ((ks * 4 + g) << 3));
      bf16x8 hh;
#pragma unroll
      for (int i = 0; i < 8; ++i)
        hh[i] = f2bf(fmaxf(bf2f(pa[i]) + bf2f(qa[i]), 0.f));
      h1[mt][ks] = hh;
    }
  }

  f32x4 acc2[2][8];
#pragma unroll
  for (int mt = 0; mt < 2; ++mt)
#pragma unroll
    for (int nt = 0; nt < 8; ++nt) acc2[mt][nt] = (f32x4){0.f, 0.f, 0.f, 0.f};

#pragma unroll
  for (int ks = 0; ks < 4; ++ks) {
#pragma unroll
    for (int nt = 0; nt < 8; ++nt) {
      bf16x8 b = *(const bf16x8*)(w2bf + ((((ks * 4 + g) * 128) + nt * 16 + lm) << 3));
      acc2[0][nt] = __builtin_amdgcn_mfma_f32_16x16x32_bf16(h1[0][ks], b, acc2[0][nt], 0, 0, 0);
      acc2[1][nt] = __builtin_amdgcn_mfma_f32_16x16x32_bf16(h1[1][ks], b, acc2[1][nt], 0, 0, 0);
    }
  }

  float part[2][4] = {{0.f, 0.f, 0.f, 0.f}, {0.f, 0.f, 0.f, 0.f}};
#pragma unroll
  for (int nt = 0; nt < 8; ++nt) {
    int n = nt * 16 + lm;
    float bias = b2[n];
    float w3n = w3v[n];
#pragma unroll
    for (int mt = 0; mt < 2; ++mt)
#pragma unroll
      for (int r = 0; r < 4; ++r) {
        float h2 = fmaxf(acc2[mt][nt][r] + bias, 0.f);
        part[mt][r] += h2 * w3n;
      }
  }
#pragma unroll
  for (int off = 1; off < 16; off <<= 1)
#pragma unroll
    for (int mt = 0; mt < 2; ++mt)
#pragma unroll
      for (int r = 0; r < 4; ++r)
        part[mt][r] += __shfl_xor(part[mt][r], off, 64);
  if (lm == 0) {
    float b3s = b3[0];
#pragma unroll
    for (int mt = 0; mt < 2; ++mt)
#pragma unroll
      for (int r = 0; r < 4; ++r)
        s_out[eb + mt * 16 + 4 * g + r] = part[mt][r] + b3s;
  }
}

// ---------------------------------------------------------------------------
// Softmax + weighted aggregation. One wave per node; inner loop processes
// 4 edges in parallel (16-lane groups own 32B of the embedding row).
// ---------------------------------------------------------------------------
__global__ __launch_bounds__(256) void agg2_kernel(
    const int* __restrict__ nodes, const int* __restrict__ neigh_idx,
    const float* __restrict__ u2e, const float* __restrict__ s,
    const int* __restrict__ off, float* __restrict__ out) {
  const int lane = threadIdx.x & 63, wv = threadIdx.x >> 6;
  const int node = blockIdx.x * 4 + wv;
  const int lo = off[node], hi = off[node + 1];
  float* orow = out + (size_t)node * EMBED;

  if (lo >= hi) {
    const float* src = u2e + (size_t)nodes[node] * EMBED;
    orow[lane] = src[lane];
    orow[lane + 64] = src[lane + 64];
    return;
  }

  float mx = -3.402823466e38f;
  for (int e = lo + lane; e < hi; e += 64) mx = fmaxf(mx, s[e]);
#pragma unroll
  for (int o = 32; o >= 1; o >>= 1) mx = fmaxf(mx, __shfl_xor(mx, o, 64));

  float sum = 0.f;
  for (int e = lo + lane; e < hi; e += 64) sum += expf(s[e] - mx);
#pragma unroll
  for (int o = 32; o >= 1; o >>= 1) sum += __shfl_xor(sum, o, 64);
  const float inv = 1.0f / sum;

  const int eg = lane >> 4, ld = lane & 15;
  f32x4 a0 = (f32x4){0.f, 0.f, 0.f, 0.f};
  f32x4 a1 = (f32x4){0.f, 0.f, 0.f, 0.f};
  for (int e = lo + eg; e < hi; e += 4) {
    float w = expf(s[e] - mx) * inv;
    const float* row = u2e + (size_t)neigh_idx[e] * EMBED + ld * 8;
    f32x4 r0 = *(const f32x4*)row;
    f32x4 r1 = *(const f32x4*)(row + 4);
    a0 += w * r0;
    a1 += w * r1;
  }
#pragma unroll
  for (int o = 16; o <= 32; o <<= 1) {
#pragma unroll
    for (int c = 0; c < 4; ++c) {
      a0[c] += __shfl_xor(a0[c], o, 64);
      a1[c] += __shfl_xor(a1[c], o, 64);
    }
  }
  if (eg == 0) {
    *(f32x4*)(orow + ld * 8) = a0;
    *(f32x4*)(orow + ld * 8 + 4) = a1;
  }
}

// ---------------------------------------------------------------------------
extern "C" void kernel_launch(void* const* d_in, const int* in_sizes, int n_in,
                              void* d_out, int out_size, void* d_ws, size_t ws_size,
                              hipStream_t stream) {
  const int* nodes  = (const int*)d_in[0];
  const int* neigh  = (const int*)d_in[1];
  const int* segs   = (const int*)d_in[2];
  const float* u2e  = (const float*)d_in[3];
  const float* w1   = (const float*)d_in[4];
  const float* b1   = (const float*)d_in[5];
  const float* w2   = (const float*)d_in[6];
  const float* b2   = (const float*)d_in[7];
  const float* w3   = (const float*)d_in[8];
  const float* b3   = (const float*)d_in[9];
  float* out = (float*)d_out;

  char* ws = (char*)d_ws;
  short* w1a  = (short*)(ws);                    // 32 KiB
  short* w1b  = (short*)(ws + 32768);            // 32 KiB
  short* w2bf = (short*)(ws + 65536);            // 32 KiB
  float* s    = (float*)(ws + 98304);            // 1.28 MB
  int*   off  = (int*)(ws + 1378304);            // 40 KB
  short* P_sw = (short*)(ws + 1418752);          // 25.6 MB
  short* Q_sw = (short*)(ws + 27018752);         // 2.56 MB

  hipLaunchKernelGGL(prep_kernel, dim3(1250), dim3(256), 0, stream,
                     segs, w1, w2, off, w1a, w1b, w2bf);
  hipLaunchKernelGGL(row_gemm2_kernel, dim3(PBLOCKS + QBLOCKS), dim3(256), 0, stream,
                     u2e, nodes, w1a, w1b, b1, P_sw, Q_sw);
  hipLaunchKernelGGL(scores2_kernel, dim3(2500), dim3(256), 0, stream,
                     neigh, segs, P_sw, Q_sw, w2bf, b2, w3, b3, s);
  hipLaunchKernelGGL(agg2_kernel, dim3(2500), dim3(256), 0, stream,
                     nodes, neigh, u2e, s, off, out);
}

// Round 7
// 176.951 us; speedup vs baseline: 1.1921x; 1.0799x over previous
//
#include <hip/hip_runtime.h>

#define EMBED 128
#define NEDGES 320000
#define NNODES 10000
#define NUSERS 100000
#define PBLK3 1563    // ceil(100000/64)
#define QBLK3 157     // ceil(10000/64)

typedef __attribute__((ext_vector_type(4))) float f32x4;
typedef __attribute__((ext_vector_type(8))) short bf16x8;

__device__ __forceinline__ short f2bf(float f) {
  union { float f; unsigned u; } v; v.f = f;
  unsigned r = v.u + 0x7fffu + ((v.u >> 16) & 1u);
  return (short)(r >> 16);
}
__device__ __forceinline__ float bf2f(short s) {
  union { unsigned u; float f; } v;
  v.u = ((unsigned)(unsigned short)s) << 16;
  return v.f;
}

// ---------------------------------------------------------------------------
// Prep kernel: seg offsets + W1/W2 -> bf16 B-fragment layout.
// Fragment: element e of lane-group g at col n covers k = 32ks+16(e>>2)+4g+(e&3),
// stored at [((ks*4+g)*128 + n)*8 + e].
// ---------------------------------------------------------------------------
__global__ __launch_bounds__(256) void prep_kernel(
    const int* __restrict__ seg_ids, const float* __restrict__ w1,
    const float* __restrict__ w2, int* __restrict__ off,
    short* __restrict__ w1a, short* __restrict__ w1b, short* __restrict__ w2bf) {
  int tid = blockIdx.x * 256 + threadIdx.x;
  if (tid < NEDGES) {
    int cur = seg_ids[tid];
    int prev = (tid == 0) ? -1 : seg_ids[tid - 1];
    for (int n = prev + 1; n <= cur; ++n) off[n] = tid;
    if (tid == NEDGES - 1)
      for (int n = cur + 1; n <= NNODES; ++n) off[n] = NEDGES;
  }
  if (tid < 128 * 256) {
    int n = tid >> 8, k = tid & 255;
    int kk = k & 127;
    int ks = kk >> 5, g = (kk >> 2) & 3, h = (kk >> 4) & 1, j = kk & 3;
    short* dst = (k < 128) ? w1a : w1b;
    dst[(((ks * 4 + g) * 128 + n) << 3) + (h << 2) + j] = f2bf(w1[tid]);
  }
  if (tid < 128 * 128) {
    int n = tid >> 7, kk = tid & 127;
    int ks = kk >> 5, g = (kk >> 2) & 3, h = (kk >> 4) & 1, j = kk & 3;
    w2bf[(((ks * 4 + g) * 128 + n) << 3) + (h << 2) + j] = f2bf(w2[tid]);
  }
}

// ---------------------------------------------------------------------------
// Row-GEMM v3 (latency-hiding restructure):
//   - 16 rows/wave, 64 rows/block -> 1720 blocks (6.7/CU vs 3.4 before)
//   - weights staged in 32KB LDS once per block (B-reads: L2 -> LDS)
//   - store-staging overlaid on the weight LDS after a barrier (LDS stays
//     32KB -> 5 blocks/CU resident)
// No early returns: block-wide barriers require all threads present.
// ---------------------------------------------------------------------------
__global__ __launch_bounds__(256) void row_gemm3_kernel(
    const float* __restrict__ u2e, const int* __restrict__ nodes,
    const short* __restrict__ w1a, const short* __restrict__ w1b,
    const float* __restrict__ b1,
    short* __restrict__ P_sw, short* __restrict__ Q_sw) {
  __shared__ short lds[16384];  // 32 KB weights; reused as store stage later

  const int tid = threadIdx.x;
  const int lane = tid & 63, wv = tid >> 6;
  const int g = lane >> 4, lm = lane & 15;

  const bool isQ = blockIdx.x >= PBLK3;
  const int blk = isQ ? (int)blockIdx.x - PBLK3 : (int)blockIdx.x;
  const int nrows = isQ ? NNODES : NUSERS;
  const short* wbf = isQ ? w1b : w1a;
  short* out = isQ ? Q_sw : P_sw;

  // Stage swizzled weights -> LDS (coalesced 16B/lane x 8).
#pragma unroll
  for (int i = 0; i < 8; ++i) {
    int o = (i * 256 + tid) << 3;
    *(bf16x8*)&lds[o] = *(const bf16x8*)&wbf[o];
  }
  __syncthreads();

  const int rb = blk * 64 + wv * 16;

  // A gather: row rb+lm (clamped), convert to bf16 fragments.
  {
    // nothing
  }
  int row = rb + lm;
  int rc = row < nrows ? row : nrows - 1;
  const float* src = u2e + (size_t)(isQ ? nodes[rc] : rc) * EMBED;
  bf16x8 af[4];
#pragma unroll
  for (int ks = 0; ks < 4; ++ks) {
    const float* p = src + 32 * ks + 4 * g;
    f32x4 lo = *(const f32x4*)p;
    f32x4 hi = *(const f32x4*)(p + 16);
    bf16x8 a;
    a[0] = f2bf(lo.x); a[1] = f2bf(lo.y); a[2] = f2bf(lo.z); a[3] = f2bf(lo.w);
    a[4] = f2bf(hi.x); a[5] = f2bf(hi.y); a[6] = f2bf(hi.z); a[7] = f2bf(hi.w);
    af[ks] = a;
  }

  f32x4 acc[8];
#pragma unroll
  for (int nt = 0; nt < 8; ++nt) acc[nt] = (f32x4){0.f, 0.f, 0.f, 0.f};

#pragma unroll
  for (int ks = 0; ks < 4; ++ks) {
#pragma unroll
    for (int nt = 0; nt < 8; ++nt) {
      bf16x8 b = *(const bf16x8*)&lds[((((ks * 4 + g) * 128) + nt * 16 + lm) << 3)];
      acc[nt] = __builtin_amdgcn_mfma_f32_16x16x32_bf16(af[ks], b, acc[nt], 0, 0, 0);
    }
  }
  __syncthreads();  // all waves done reading weights; LDS is reusable

  // Epilogue: D col n = nt*16+lm, row m = 4g+r -> swizzled A-frag layout,
  // staged per-wave in LDS then stored coalesced (4 lanes/row, 64B each).
  short* st = &lds[wv * 2176];  // 16 rows x 136 shorts (pad vs 128)
#pragma unroll
  for (int nt = 0; nt < 8; ++nt) {
    float bs = isQ ? b1[nt * 16 + lm] : 0.f;
    int fragoff = (((nt >> 1) * 4 + (lm >> 2)) << 3) + ((nt & 1) << 2) + (lm & 3);
#pragma unroll
    for (int r = 0; r < 4; ++r)
      st[(4 * g + r) * 136 + fragoff] = f2bf(acc[nt][r] + bs);
  }
  // Wave-local drain: this wave wrote its slice, this wave reads it.
  asm volatile("s_waitcnt lgkmcnt(0)" ::: "memory");

  const int srow = lane >> 2, q = lane & 3;
  const int u = rb + srow;
  if (u < nrows) {
    short* orow = out + (size_t)u * 128 + q * 32;
    const short* sr = st + srow * 136 + q * 32;
#pragma unroll
    for (int i = 0; i < 4; ++i)
      *(bf16x8*)(orow + i * 8) = *(const bf16x8*)(sr + i * 8);
  }
}

// ---------------------------------------------------------------------------
// Scores: s[e] = w3 . relu(W2 . relu(P[neigh] + Q[seg]) + b2) + b3
// h1 fragments built directly in registers from pre-swizzled P/Q. No LDS.
// ---------------------------------------------------------------------------
__global__ __launch_bounds__(256) void scores2_kernel(
    const int* __restrict__ neigh_idx, const int* __restrict__ seg_ids,
    const short* __restrict__ P_sw, const short* __restrict__ Q_sw,
    const short* __restrict__ w2bf, const float* __restrict__ b2,
    const float* __restrict__ w3v, const float* __restrict__ b3,
    float* __restrict__ s_out) {
  const int lane = threadIdx.x & 63, wv = threadIdx.x >> 6;
  const int g = lane >> 4, lm = lane & 15;
  const int eb = (blockIdx.x * 4 + wv) * 32;

  bf16x8 h1[2][4];
#pragma unroll
  for (int mt = 0; mt < 2; ++mt) {
    int e = eb + mt * 16 + lm;
    const short* pb = P_sw + (size_t)neigh_idx[e] * 128;
    const short* qb = Q_sw + (size_t)seg_ids[e] * 128;
#pragma unroll
    for (int ks = 0; ks < 4; ++ks) {
      bf16x8 pa = *(const bf16x8*)(pb + ((ks * 4 + g) << 3));
      bf16x8 qa = *(const bf16x8*)(qb + ((ks * 4 + g) << 3));
      bf16x8 hh;
#pragma unroll
      for (int i = 0; i < 8; ++i)
        hh[i] = f2bf(fmaxf(bf2f(pa[i]) + bf2f(qa[i]), 0.f));
      h1[mt][ks] = hh;
    }
  }

  f32x4 acc2[2][8];
#pragma unroll
  for (int mt = 0; mt < 2; ++mt)
#pragma unroll
    for (int nt = 0; nt < 8; ++nt) acc2[mt][nt] = (f32x4){0.f, 0.f, 0.f, 0.f};

#pragma unroll
  for (int ks = 0; ks < 4; ++ks) {
#pragma unroll
    for (int nt = 0; nt < 8; ++nt) {
      bf16x8 b = *(const bf16x8*)(w2bf + ((((ks * 4 + g) * 128) + nt * 16 + lm) << 3));
      acc2[0][nt] = __builtin_amdgcn_mfma_f32_16x16x32_bf16(h1[0][ks], b, acc2[0][nt], 0, 0, 0);
      acc2[1][nt] = __builtin_amdgcn_mfma_f32_16x16x32_bf16(h1[1][ks], b, acc2[1][nt], 0, 0, 0);
    }
  }

  float part[2][4] = {{0.f, 0.f, 0.f, 0.f}, {0.f, 0.f, 0.f, 0.f}};
#pragma unroll
  for (int nt = 0; nt < 8; ++nt) {
    int n = nt * 16 + lm;
    float bias = b2[n];
    float w3n = w3v[n];
#pragma unroll
    for (int mt = 0; mt < 2; ++mt)
#pragma unroll
      for (int r = 0; r < 4; ++r) {
        float h2 = fmaxf(acc2[mt][nt][r] + bias, 0.f);
        part[mt][r] += h2 * w3n;
      }
  }
#pragma unroll
  for (int off = 1; off < 16; off <<= 1)
#pragma unroll
    for (int mt = 0; mt < 2; ++mt)
#pragma unroll
      for (int r = 0; r < 4; ++r)
        part[mt][r] += __shfl_xor(part[mt][r], off, 64);
  if (lm == 0) {
    float b3s = b3[0];
#pragma unroll
    for (int mt = 0; mt < 2; ++mt)
#pragma unroll
      for (int r = 0; r < 4; ++r)
        s_out[eb + mt * 16 + 4 * g + r] = part[mt][r] + b3s;
  }
}

// ---------------------------------------------------------------------------
// Softmax + weighted aggregation. One wave per node; inner loop processes
// 4 edges in parallel (16-lane groups own 32B of the embedding row).
// ---------------------------------------------------------------------------
__global__ __launch_bounds__(256) void agg2_kernel(
    const int* __restrict__ nodes, const int* __restrict__ neigh_idx,
    const float* __restrict__ u2e, const float* __restrict__ s,
    const int* __restrict__ off, float* __restrict__ out) {
  const int lane = threadIdx.x & 63, wv = threadIdx.x >> 6;
  const int node = blockIdx.x * 4 + wv;
  const int lo = off[node], hi = off[node + 1];
  float* orow = out + (size_t)node * EMBED;

  if (lo >= hi) {
    const float* src = u2e + (size_t)nodes[node] * EMBED;
    orow[lane] = src[lane];
    orow[lane + 64] = src[lane + 64];
    return;
  }

  float mx = -3.402823466e38f;
  for (int e = lo + lane; e < hi; e += 64) mx = fmaxf(mx, s[e]);
#pragma unroll
  for (int o = 32; o >= 1; o >>= 1) mx = fmaxf(mx, __shfl_xor(mx, o, 64));

  float sum = 0.f;
  for (int e = lo + lane; e < hi; e += 64) sum += expf(s[e] - mx);
#pragma unroll
  for (int o = 32; o >= 1; o >>= 1) sum += __shfl_xor(sum, o, 64);
  const float inv = 1.0f / sum;

  const int eg = lane >> 4, ld = lane & 15;
  f32x4 a0 = (f32x4){0.f, 0.f, 0.f, 0.f};
  f32x4 a1 = (f32x4){0.f, 0.f, 0.f, 0.f};
  for (int e = lo + eg; e < hi; e += 4) {
    float w = expf(s[e] - mx) * inv;
    const float* row = u2e + (size_t)neigh_idx[e] * EMBED + ld * 8;
    f32x4 r0 = *(const f32x4*)row;
    f32x4 r1 = *(const f32x4*)(row + 4);
    a0 += w * r0;
    a1 += w * r1;
  }
#pragma unroll
  for (int o = 16; o <= 32; o <<= 1) {
#pragma unroll
    for (int c = 0; c < 4; ++c) {
      a0[c] += __shfl_xor(a0[c], o, 64);
      a1[c] += __shfl_xor(a1[c], o, 64);
    }
  }
  if (eg == 0) {
    *(f32x4*)(orow + ld * 8) = a0;
    *(f32x4*)(orow + ld * 8 + 4) = a1;
  }
}

// ---------------------------------------------------------------------------
extern "C" void kernel_launch(void* const* d_in, const int* in_sizes, int n_in,
                              void* d_out, int out_size, void* d_ws, size_t ws_size,
                              hipStream_t stream) {
  const int* nodes  = (const int*)d_in[0];
  const int* neigh  = (const int*)d_in[1];
  const int* segs   = (const int*)d_in[2];
  const float* u2e  = (const float*)d_in[3];
  const float* w1   = (const float*)d_in[4];
  const float* b1   = (const float*)d_in[5];
  const float* w2   = (const float*)d_in[6];
  const float* b2   = (const float*)d_in[7];
  const float* w3   = (const float*)d_in[8];
  const float* b3   = (const float*)d_in[9];
  float* out = (float*)d_out;

  char* ws = (char*)d_ws;
  short* w1a  = (short*)(ws);                    // 32 KiB
  short* w1b  = (short*)(ws + 32768);            // 32 KiB
  short* w2bf = (short*)(ws + 65536);            // 32 KiB
  float* s    = (float*)(ws + 98304);            // 1.28 MB
  int*   off  = (int*)(ws + 1378304);            // 40 KB
  short* P_sw = (short*)(ws + 1418752);          // 25.6 MB
  short* Q_sw = (short*)(ws + 27018752);         // 2.56 MB

  hipLaunchKernelGGL(prep_kernel, dim3(1250), dim3(256), 0, stream,
                     segs, w1, w2, off, w1a, w1b, w2bf);
  hipLaunchKernelGGL(row_gemm3_kernel, dim3(PBLK3 + QBLK3), dim3(256), 0, stream,
                     u2e, nodes, w1a, w1b, b1, P_sw, Q_sw);
  hipLaunchKernelGGL(scores2_kernel, dim3(2500), dim3(256), 0, stream,
                     neigh, segs, P_sw, Q_sw, w2bf, b2, w3, b3, s);
  hipLaunchKernelGGL(agg2_kernel, dim3(2500), dim3(256), 0, stream,
                     nodes, neigh, u2e, s, off, out);
}

// Round 8
// 171.473 us; speedup vs baseline: 1.2302x; 1.0319x over previous
//
#include <hip/hip_runtime.h>

#define EMBED 128
#define NEDGES 320000
#define NNODES 10000
#define NUSERS 100000
#define PBLK3 1563    // ceil(100000/64)
#define QBLK3 157     // ceil(10000/64)

typedef __attribute__((ext_vector_type(4))) float f32x4;
typedef __attribute__((ext_vector_type(8))) short bf16x8;

__device__ __forceinline__ short f2bf(float f) {
  union { float f; unsigned u; } v; v.f = f;
  unsigned r = v.u + 0x7fffu + ((v.u >> 16) & 1u);
  return (short)(r >> 16);
}
// Truncating f32->bf16 (1 op vs 3). Used only for h1: softmax is
// shift-invariant so the common downward bias cancels; spread ~2x RNE.
__device__ __forceinline__ short f2bf_trunc(float f) {
  union { float f; unsigned u; } v; v.f = f;
  return (short)(v.u >> 16);
}
__device__ __forceinline__ float bf2f(short s) {
  union { unsigned u; float f; } v;
  v.u = ((unsigned)(unsigned short)s) << 16;
  return v.f;
}

// ---------------------------------------------------------------------------
// Prep kernel: seg offsets + W1/W2 -> bf16 B-fragment layout.
// Fragment: element e of lane-group g at col n covers k = 32ks+16(e>>2)+4g+(e&3),
// stored at [((ks*4+g)*128 + n)*8 + e].
// ---------------------------------------------------------------------------
__global__ __launch_bounds__(256) void prep_kernel(
    const int* __restrict__ seg_ids, const float* __restrict__ w1,
    const float* __restrict__ w2, int* __restrict__ off,
    short* __restrict__ w1a, short* __restrict__ w1b, short* __restrict__ w2bf) {
  int tid = blockIdx.x * 256 + threadIdx.x;
  if (tid < NEDGES) {
    int cur = seg_ids[tid];
    int prev = (tid == 0) ? -1 : seg_ids[tid - 1];
    for (int n = prev + 1; n <= cur; ++n) off[n] = tid;
    if (tid == NEDGES - 1)
      for (int n = cur + 1; n <= NNODES; ++n) off[n] = NEDGES;
  }
  if (tid < 128 * 256) {
    int n = tid >> 8, k = tid & 255;
    int kk = k & 127;
    int ks = kk >> 5, g = (kk >> 2) & 3, h = (kk >> 4) & 1, j = kk & 3;
    short* dst = (k < 128) ? w1a : w1b;
    dst[(((ks * 4 + g) * 128 + n) << 3) + (h << 2) + j] = f2bf(w1[tid]);
  }
  if (tid < 128 * 128) {
    int n = tid >> 7, kk = tid & 127;
    int ks = kk >> 5, g = (kk >> 2) & 3, h = (kk >> 4) & 1, j = kk & 3;
    w2bf[(((ks * 4 + g) * 128 + n) << 3) + (h << 2) + j] = f2bf(w2[tid]);
  }
}

// ---------------------------------------------------------------------------
// Row-GEMM v3: 16 rows/wave, 64 rows/block; weights staged in 32KB LDS once
// per block; store-staging overlaid on the weight LDS after a barrier.
// ---------------------------------------------------------------------------
__global__ __launch_bounds__(256) void row_gemm3_kernel(
    const float* __restrict__ u2e, const int* __restrict__ nodes,
    const short* __restrict__ w1a, const short* __restrict__ w1b,
    const float* __restrict__ b1,
    short* __restrict__ P_sw, short* __restrict__ Q_sw) {
  __shared__ short lds[16384];  // 32 KB weights; reused as store stage later

  const int tid = threadIdx.x;
  const int lane = tid & 63, wv = tid >> 6;
  const int g = lane >> 4, lm = lane & 15;

  const bool isQ = blockIdx.x >= PBLK3;
  const int blk = isQ ? (int)blockIdx.x - PBLK3 : (int)blockIdx.x;
  const int nrows = isQ ? NNODES : NUSERS;
  const short* wbf = isQ ? w1b : w1a;
  short* out = isQ ? Q_sw : P_sw;

#pragma unroll
  for (int i = 0; i < 8; ++i) {
    int o = (i * 256 + tid) << 3;
    *(bf16x8*)&lds[o] = *(const bf16x8*)&wbf[o];
  }
  __syncthreads();

  const int rb = blk * 64 + wv * 16;
  int row = rb + lm;
  int rc = row < nrows ? row : nrows - 1;
  const float* src = u2e + (size_t)(isQ ? nodes[rc] : rc) * EMBED;
  bf16x8 af[4];
#pragma unroll
  for (int ks = 0; ks < 4; ++ks) {
    const float* p = src + 32 * ks + 4 * g;
    f32x4 lo = *(const f32x4*)p;
    f32x4 hi = *(const f32x4*)(p + 16);
    bf16x8 a;
    a[0] = f2bf(lo.x); a[1] = f2bf(lo.y); a[2] = f2bf(lo.z); a[3] = f2bf(lo.w);
    a[4] = f2bf(hi.x); a[5] = f2bf(hi.y); a[6] = f2bf(hi.z); a[7] = f2bf(hi.w);
    af[ks] = a;
  }

  f32x4 acc[8];
#pragma unroll
  for (int nt = 0; nt < 8; ++nt) acc[nt] = (f32x4){0.f, 0.f, 0.f, 0.f};

#pragma unroll
  for (int ks = 0; ks < 4; ++ks) {
#pragma unroll
    for (int nt = 0; nt < 8; ++nt) {
      bf16x8 b = *(const bf16x8*)&lds[((((ks * 4 + g) * 128) + nt * 16 + lm) << 3)];
      acc[nt] = __builtin_amdgcn_mfma_f32_16x16x32_bf16(af[ks], b, acc[nt], 0, 0, 0);
    }
  }
  __syncthreads();  // all waves done reading weights; LDS is reusable

  short* st = &lds[wv * 2176];  // 16 rows x 136 shorts (pad vs 128)
#pragma unroll
  for (int nt = 0; nt < 8; ++nt) {
    float bs = isQ ? b1[nt * 16 + lm] : 0.f;
    int fragoff = (((nt >> 1) * 4 + (lm >> 2)) << 3) + ((nt & 1) << 2) + (lm & 3);
#pragma unroll
    for (int r = 0; r < 4; ++r)
      st[(4 * g + r) * 136 + fragoff] = f2bf(acc[nt][r] + bs);
  }
  asm volatile("s_waitcnt lgkmcnt(0)" ::: "memory");

  const int srow = lane >> 2, q = lane & 3;
  const int u = rb + srow;
  if (u < nrows) {
    short* orow = out + (size_t)u * 128 + q * 32;
    const short* sr = st + srow * 136 + q * 32;
#pragma unroll
    for (int i = 0; i < 4; ++i)
      *(bf16x8*)(orow + i * 8) = *(const bf16x8*)(sr + i * 8);
  }
}

// ---------------------------------------------------------------------------
// Scores v3: s[e] = w3 . relu(W2 . relu(P[neigh] + Q[seg]) + b2) + b3
//  - w2 fragments staged in 32KB LDS once per block (was: L1/L2 re-read
//    32KB per wave -> ~320MB cache traffic; now 80MB)
//  - h1 conversion uses truncating bf16 (1 VALU op vs 3)
// ---------------------------------------------------------------------------
__global__ __launch_bounds__(256) void scores3_kernel(
    const int* __restrict__ neigh_idx, const int* __restrict__ seg_ids,
    const short* __restrict__ P_sw, const short* __restrict__ Q_sw,
    const short* __restrict__ w2bf, const float* __restrict__ b2,
    const float* __restrict__ w3v, const float* __restrict__ b3,
    float* __restrict__ s_out) {
  __shared__ short w2l[16384];  // 32 KB

  const int tid = threadIdx.x;
  const int lane = tid & 63, wv = tid >> 6;
  const int g = lane >> 4, lm = lane & 15;
  const int eb = (blockIdx.x * 4 + wv) * 32;

#pragma unroll
  for (int i = 0; i < 8; ++i) {
    int o = (i * 256 + tid) << 3;
    *(bf16x8*)&w2l[o] = *(const bf16x8*)&w2bf[o];
  }
  __syncthreads();

  bf16x8 h1[2][4];
#pragma unroll
  for (int mt = 0; mt < 2; ++mt) {
    int e = eb + mt * 16 + lm;
    const short* pb = P_sw + (size_t)neigh_idx[e] * 128;
    const short* qb = Q_sw + (size_t)seg_ids[e] * 128;
#pragma unroll
    for (int ks = 0; ks < 4; ++ks) {
      bf16x8 pa = *(const bf16x8*)(pb + ((ks * 4 + g) << 3));
      bf16x8 qa = *(const bf16x8*)(qb + ((ks * 4 + g) << 3));
      bf16x8 hh;
#pragma unroll
      for (int i = 0; i < 8; ++i)
        hh[i] = f2bf_trunc(fmaxf(bf2f(pa[i]) + bf2f(qa[i]), 0.f));
      h1[mt][ks] = hh;
    }
  }

  f32x4 acc2[2][8];
#pragma unroll
  for (int mt = 0; mt < 2; ++mt)
#pragma unroll
    for (int nt = 0; nt < 8; ++nt) acc2[mt][nt] = (f32x4){0.f, 0.f, 0.f, 0.f};

#pragma unroll
  for (int ks = 0; ks < 4; ++ks) {
#pragma unroll
    for (int nt = 0; nt < 8; ++nt) {
      bf16x8 b = *(const bf16x8*)&w2l[((((ks * 4 + g) * 128) + nt * 16 + lm) << 3)];
      acc2[0][nt] = __builtin_amdgcn_mfma_f32_16x16x32_bf16(h1[0][ks], b, acc2[0][nt], 0, 0, 0);
      acc2[1][nt] = __builtin_amdgcn_mfma_f32_16x16x32_bf16(h1[1][ks], b, acc2[1][nt], 0, 0, 0);
    }
  }

  float part[2][4] = {{0.f, 0.f, 0.f, 0.f}, {0.f, 0.f, 0.f, 0.f}};
#pragma unroll
  for (int nt = 0; nt < 8; ++nt) {
    int n = nt * 16 + lm;
    float bias = b2[n];
    float w3n = w3v[n];
#pragma unroll
    for (int mt = 0; mt < 2; ++mt)
#pragma unroll
      for (int r = 0; r < 4; ++r) {
        float h2 = fmaxf(acc2[mt][nt][r] + bias, 0.f);
        part[mt][r] += h2 * w3n;
      }
  }
#pragma unroll
  for (int off = 1; off < 16; off <<= 1)
#pragma unroll
    for (int mt = 0; mt < 2; ++mt)
#pragma unroll
      for (int r = 0; r < 4; ++r)
        part[mt][r] += __shfl_xor(part[mt][r], off, 64);
  if (lm == 0) {
    float b3s = b3[0];
#pragma unroll
    for (int mt = 0; mt < 2; ++mt)
#pragma unroll
      for (int r = 0; r < 4; ++r)
        s_out[eb + mt * 16 + 4 * g + r] = part[mt][r] + b3s;
  }
}

// ---------------------------------------------------------------------------
// Softmax + weighted aggregation v3. One wave per node; weighted loop
// unrolled 2x (8 edge-rows in flight per wave vs 4).
// ---------------------------------------------------------------------------
__global__ __launch_bounds__(256) void agg3_kernel(
    const int* __restrict__ nodes, const int* __restrict__ neigh_idx,
    const float* __restrict__ u2e, const float* __restrict__ s,
    const int* __restrict__ off, float* __restrict__ out) {
  const int lane = threadIdx.x & 63, wv = threadIdx.x >> 6;
  const int node = blockIdx.x * 4 + wv;
  const int lo = off[node], hi = off[node + 1];
  float* orow = out + (size_t)node * EMBED;

  if (lo >= hi) {
    const float* src = u2e + (size_t)nodes[node] * EMBED;
    orow[lane] = src[lane];
    orow[lane + 64] = src[lane + 64];
    return;
  }

  float mx = -3.402823466e38f;
  for (int e = lo + lane; e < hi; e += 64) mx = fmaxf(mx, s[e]);
#pragma unroll
  for (int o = 32; o >= 1; o >>= 1) mx = fmaxf(mx, __shfl_xor(mx, o, 64));

  float sum = 0.f;
  for (int e = lo + lane; e < hi; e += 64) sum += expf(s[e] - mx);
#pragma unroll
  for (int o = 32; o >= 1; o >>= 1) sum += __shfl_xor(sum, o, 64);
  const float inv = 1.0f / sum;

  const int eg = lane >> 4, ld = lane & 15;
  f32x4 a0 = (f32x4){0.f, 0.f, 0.f, 0.f};
  f32x4 a1 = (f32x4){0.f, 0.f, 0.f, 0.f};
  f32x4 b0 = (f32x4){0.f, 0.f, 0.f, 0.f};
  f32x4 b1v = (f32x4){0.f, 0.f, 0.f, 0.f};
  int e = lo + eg;
  for (; e + 4 < hi; e += 8) {  // 2 edges per group in flight
    float wA = expf(s[e] - mx) * inv;
    float wB = expf(s[e + 4] - mx) * inv;
    const float* rowA = u2e + (size_t)neigh_idx[e] * EMBED + ld * 8;
    const float* rowB = u2e + (size_t)neigh_idx[e + 4] * EMBED + ld * 8;
    f32x4 rA0 = *(const f32x4*)rowA;
    f32x4 rA1 = *(const f32x4*)(rowA + 4);
    f32x4 rB0 = *(const f32x4*)rowB;
    f32x4 rB1 = *(const f32x4*)(rowB + 4);
    a0 += wA * rA0;
    a1 += wA * rA1;
    b0 += wB * rB0;
    b1v += wB * rB1;
  }
  for (; e < hi; e += 4) {
    float w = expf(s[e] - mx) * inv;
    const float* row = u2e + (size_t)neigh_idx[e] * EMBED + ld * 8;
    f32x4 r0 = *(const f32x4*)row;
    f32x4 r1 = *(const f32x4*)(row + 4);
    a0 += w * r0;
    a1 += w * r1;
  }
  a0 += b0;
  a1 += b1v;
#pragma unroll
  for (int o = 16; o <= 32; o <<= 1) {
#pragma unroll
    for (int c = 0; c < 4; ++c) {
      a0[c] += __shfl_xor(a0[c], o, 64);
      a1[c] += __shfl_xor(a1[c], o, 64);
    }
  }
  if (eg == 0) {
    *(f32x4*)(orow + ld * 8) = a0;
    *(f32x4*)(orow + ld * 8 + 4) = a1;
  }
}

// ---------------------------------------------------------------------------
extern "C" void kernel_launch(void* const* d_in, const int* in_sizes, int n_in,
                              void* d_out, int out_size, void* d_ws, size_t ws_size,
                              hipStream_t stream) {
  const int* nodes  = (const int*)d_in[0];
  const int* neigh  = (const int*)d_in[1];
  const int* segs   = (const int*)d_in[2];
  const float* u2e  = (const float*)d_in[3];
  const float* w1   = (const float*)d_in[4];
  const float* b1   = (const float*)d_in[5];
  const float* w2   = (const float*)d_in[6];
  const float* b2   = (const float*)d_in[7];
  const float* w3   = (const float*)d_in[8];
  const float* b3   = (const float*)d_in[9];
  float* out = (float*)d_out;

  char* ws = (char*)d_ws;
  short* w1a  = (short*)(ws);                    // 32 KiB
  short* w1b  = (short*)(ws + 32768);            // 32 KiB
  short* w2bf = (short*)(ws + 65536);            // 32 KiB
  float* s    = (float*)(ws + 98304);            // 1.28 MB
  int*   off  = (int*)(ws + 1378304);            // 40 KB
  short* P_sw = (short*)(ws + 1418752);          // 25.6 MB
  short* Q_sw = (short*)(ws + 27018752);         // 2.56 MB

  hipLaunchKernelGGL(prep_kernel, dim3(1250), dim3(256), 0, stream,
                     segs, w1, w2, off, w1a, w1b, w2bf);
  hipLaunchKernelGGL(row_gemm3_kernel, dim3(PBLK3 + QBLK3), dim3(256), 0, stream,
                     u2e, nodes, w1a, w1b, b1, P_sw, Q_sw);
  hipLaunchKernelGGL(scores3_kernel, dim3(2500), dim3(256), 0, stream,
                     neigh, segs, P_sw, Q_sw, w2bf, b2, w3, b3, s);
  hipLaunchKernelGGL(agg3_kernel, dim3(2500), dim3(256), 0, stream,
                     nodes, neigh, u2e, s, off, out);
}

// Round 9
// 168.243 us; speedup vs baseline: 1.2538x; 1.0192x over previous
//
#include <hip/hip_runtime.h>

#define EMBED 128
#define NEDGES 320000
#define NNODES 10000
#define NUSERS 100000
#define PBLK3 1563    // ceil(100000/64)
#define QBLK3 157     // ceil(10000/64)

typedef __attribute__((ext_vector_type(4))) float f32x4;
typedef __attribute__((ext_vector_type(8))) short bf16x8;
typedef __attribute__((ext_vector_type(4))) short bf16x4;

__device__ __forceinline__ short f2bf(float f) {
  union { float f; unsigned u; } v; v.f = f;
  unsigned r = v.u + 0x7fffu + ((v.u >> 16) & 1u);
  return (short)(r >> 16);
}
// Truncating f32->bf16 (1 op vs 3). Used only for h1: softmax is
// shift-invariant so the common downward bias cancels; spread ~2x RNE.
__device__ __forceinline__ short f2bf_trunc(float f) {
  union { float f; unsigned u; } v; v.f = f;
  return (short)(v.u >> 16);
}
__device__ __forceinline__ float bf2f(short s) {
  union { unsigned u; float f; } v;
  v.u = ((unsigned)(unsigned short)s) << 16;
  return v.f;
}

// ---------------------------------------------------------------------------
// Prep kernel: seg offsets + W1/W2 -> bf16 B-fragment layout.
// Fragment: element e of lane-group g at col n covers k = 32ks+16(e>>2)+4g+(e&3),
// stored at [((ks*4+g)*128 + n)*8 + e].
// ---------------------------------------------------------------------------
__global__ __launch_bounds__(256) void prep_kernel(
    const int* __restrict__ seg_ids, const float* __restrict__ w1,
    const float* __restrict__ w2, int* __restrict__ off,
    short* __restrict__ w1a, short* __restrict__ w1b, short* __restrict__ w2bf) {
  int tid = blockIdx.x * 256 + threadIdx.x;
  if (tid < NEDGES) {
    int cur = seg_ids[tid];
    int prev = (tid == 0) ? -1 : seg_ids[tid - 1];
    for (int n = prev + 1; n <= cur; ++n) off[n] = tid;
    if (tid == NEDGES - 1)
      for (int n = cur + 1; n <= NNODES; ++n) off[n] = NEDGES;
  }
  if (tid < 128 * 256) {
    int n = tid >> 8, k = tid & 255;
    int kk = k & 127;
    int ks = kk >> 5, g = (kk >> 2) & 3, h = (kk >> 4) & 1, j = kk & 3;
    short* dst = (k < 128) ? w1a : w1b;
    dst[(((ks * 4 + g) * 128 + n) << 3) + (h << 2) + j] = f2bf(w1[tid]);
  }
  if (tid < 128 * 128) {
    int n = tid >> 7, kk = tid & 127;
    int ks = kk >> 5, g = (kk >> 2) & 3, h = (kk >> 4) & 1, j = kk & 3;
    w2bf[(((ks * 4 + g) * 128 + n) << 3) + (h << 2) + j] = f2bf(w2[tid]);
  }
}

// ---------------------------------------------------------------------------
// Row-GEMM v3: 16 rows/wave, 64 rows/block; weights staged in 32KB LDS once
// per block; store-staging overlaid on the weight LDS after a barrier.
// P path additionally emits a bf16 (RNE) copy of each u2e row it already
// loaded -- feeds agg4's halved-bandwidth gather.
// ---------------------------------------------------------------------------
__global__ __launch_bounds__(256) void row_gemm3_kernel(
    const float* __restrict__ u2e, const int* __restrict__ nodes,
    const short* __restrict__ w1a, const short* __restrict__ w1b,
    const float* __restrict__ b1,
    short* __restrict__ P_sw, short* __restrict__ Q_sw,
    short* __restrict__ u2e_bf) {
  __shared__ short lds[16384];  // 32 KB weights; reused as store stage later

  const int tid = threadIdx.x;
  const int lane = tid & 63, wv = tid >> 6;
  const int g = lane >> 4, lm = lane & 15;

  const bool isQ = blockIdx.x >= PBLK3;
  const int blk = isQ ? (int)blockIdx.x - PBLK3 : (int)blockIdx.x;
  const int nrows = isQ ? NNODES : NUSERS;
  const short* wbf = isQ ? w1b : w1a;
  short* out = isQ ? Q_sw : P_sw;

#pragma unroll
  for (int i = 0; i < 8; ++i) {
    int o = (i * 256 + tid) << 3;
    *(bf16x8*)&lds[o] = *(const bf16x8*)&wbf[o];
  }
  __syncthreads();

  const int rb = blk * 64 + wv * 16;
  int row = rb + lm;
  int rc = row < nrows ? row : nrows - 1;
  const float* src = u2e + (size_t)(isQ ? nodes[rc] : rc) * EMBED;
  bf16x8 af[4];
#pragma unroll
  for (int ks = 0; ks < 4; ++ks) {
    const float* p = src + 32 * ks + 4 * g;
    f32x4 lo = *(const f32x4*)p;
    f32x4 hi = *(const f32x4*)(p + 16);
    bf16x8 a;
    a[0] = f2bf(lo.x); a[1] = f2bf(lo.y); a[2] = f2bf(lo.z); a[3] = f2bf(lo.w);
    a[4] = f2bf(hi.x); a[5] = f2bf(hi.y); a[6] = f2bf(hi.z); a[7] = f2bf(hi.w);
    af[ks] = a;
    if (!isQ) {  // P path covers every user row exactly once (mod clamp dup)
      short* dst = u2e_bf + (size_t)rc * 128 + 32 * ks + 4 * g;
      *(bf16x4*)dst = (bf16x4){a[0], a[1], a[2], a[3]};
      *(bf16x4*)(dst + 16) = (bf16x4){a[4], a[5], a[6], a[7]};
    }
  }

  f32x4 acc[8];
#pragma unroll
  for (int nt = 0; nt < 8; ++nt) acc[nt] = (f32x4){0.f, 0.f, 0.f, 0.f};

#pragma unroll
  for (int ks = 0; ks < 4; ++ks) {
#pragma unroll
    for (int nt = 0; nt < 8; ++nt) {
      bf16x8 b = *(const bf16x8*)&lds[((((ks * 4 + g) * 128) + nt * 16 + lm) << 3)];
      acc[nt] = __builtin_amdgcn_mfma_f32_16x16x32_bf16(af[ks], b, acc[nt], 0, 0, 0);
    }
  }
  __syncthreads();  // all waves done reading weights; LDS is reusable

  short* st = &lds[wv * 2176];  // 16 rows x 136 shorts (pad vs 128)
#pragma unroll
  for (int nt = 0; nt < 8; ++nt) {
    float bs = isQ ? b1[nt * 16 + lm] : 0.f;
    int fragoff = (((nt >> 1) * 4 + (lm >> 2)) << 3) + ((nt & 1) << 2) + (lm & 3);
#pragma unroll
    for (int r = 0; r < 4; ++r)
      st[(4 * g + r) * 136 + fragoff] = f2bf(acc[nt][r] + bs);
  }
  asm volatile("s_waitcnt lgkmcnt(0)" ::: "memory");

  const int srow = lane >> 2, q = lane & 3;
  const int u = rb + srow;
  if (u < nrows) {
    short* orow = out + (size_t)u * 128 + q * 32;
    const short* sr = st + srow * 136 + q * 32;
#pragma unroll
    for (int i = 0; i < 4; ++i)
      *(bf16x8*)(orow + i * 8) = *(const bf16x8*)(sr + i * 8);
  }
}

// ---------------------------------------------------------------------------
// Scores v3: s[e] = w3 . relu(W2 . relu(P[neigh] + Q[seg]) + b2) + b3
// w2 fragments staged in 32KB LDS once per block; truncating h1 conversion.
// ---------------------------------------------------------------------------
__global__ __launch_bounds__(256) void scores3_kernel(
    const int* __restrict__ neigh_idx, const int* __restrict__ seg_ids,
    const short* __restrict__ P_sw, const short* __restrict__ Q_sw,
    const short* __restrict__ w2bf, const float* __restrict__ b2,
    const float* __restrict__ w3v, const float* __restrict__ b3,
    float* __restrict__ s_out) {
  __shared__ short w2l[16384];  // 32 KB

  const int tid = threadIdx.x;
  const int lane = tid & 63, wv = tid >> 6;
  const int g = lane >> 4, lm = lane & 15;
  const int eb = (blockIdx.x * 4 + wv) * 32;

#pragma unroll
  for (int i = 0; i < 8; ++i) {
    int o = (i * 256 + tid) << 3;
    *(bf16x8*)&w2l[o] = *(const bf16x8*)&w2bf[o];
  }
  __syncthreads();

  bf16x8 h1[2][4];
#pragma unroll
  for (int mt = 0; mt < 2; ++mt) {
    int e = eb + mt * 16 + lm;
    const short* pb = P_sw + (size_t)neigh_idx[e] * 128;
    const short* qb = Q_sw + (size_t)seg_ids[e] * 128;
#pragma unroll
    for (int ks = 0; ks < 4; ++ks) {
      bf16x8 pa = *(const bf16x8*)(pb + ((ks * 4 + g) << 3));
      bf16x8 qa = *(const bf16x8*)(qb + ((ks * 4 + g) << 3));
      bf16x8 hh;
#pragma unroll
      for (int i = 0; i < 8; ++i)
        hh[i] = f2bf_trunc(fmaxf(bf2f(pa[i]) + bf2f(qa[i]), 0.f));
      h1[mt][ks] = hh;
    }
  }

  f32x4 acc2[2][8];
#pragma unroll
  for (int mt = 0; mt < 2; ++mt)
#pragma unroll
    for (int nt = 0; nt < 8; ++nt) acc2[mt][nt] = (f32x4){0.f, 0.f, 0.f, 0.f};

#pragma unroll
  for (int ks = 0; ks < 4; ++ks) {
#pragma unroll
    for (int nt = 0; nt < 8; ++nt) {
      bf16x8 b = *(const bf16x8*)&w2l[((((ks * 4 + g) * 128) + nt * 16 + lm) << 3)];
      acc2[0][nt] = __builtin_amdgcn_mfma_f32_16x16x32_bf16(h1[0][ks], b, acc2[0][nt], 0, 0, 0);
      acc2[1][nt] = __builtin_amdgcn_mfma_f32_16x16x32_bf16(h1[1][ks], b, acc2[1][nt], 0, 0, 0);
    }
  }

  float part[2][4] = {{0.f, 0.f, 0.f, 0.f}, {0.f, 0.f, 0.f, 0.f}};
#pragma unroll
  for (int nt = 0; nt < 8; ++nt) {
    int n = nt * 16 + lm;
    float bias = b2[n];
    float w3n = w3v[n];
#pragma unroll
    for (int mt = 0; mt < 2; ++mt)
#pragma unroll
      for (int r = 0; r < 4; ++r) {
        float h2 = fmaxf(acc2[mt][nt][r] + bias, 0.f);
        part[mt][r] += h2 * w3n;
      }
  }
#pragma unroll
  for (int off = 1; off < 16; off <<= 1)
#pragma unroll
    for (int mt = 0; mt < 2; ++mt)
#pragma unroll
      for (int r = 0; r < 4; ++r)
        part[mt][r] += __shfl_xor(part[mt][r], off, 64);
  if (lm == 0) {
    float b3s = b3[0];
#pragma unroll
    for (int mt = 0; mt < 2; ++mt)
#pragma unroll
      for (int r = 0; r < 4; ++r)
        s_out[eb + mt * 16 + 4 * g + r] = part[mt][r] + b3s;
  }
}

// ---------------------------------------------------------------------------
// Softmax + weighted aggregation v4. One wave per node; 2x-unrolled loop;
// neighbor rows gathered as bf16 (256B/edge, half of fp32) from u2e_bf,
// fp32 accumulate.  Zero-degree fallback stays exact fp32.
// ---------------------------------------------------------------------------
__global__ __launch_bounds__(256) void agg4_kernel(
    const int* __restrict__ nodes, const int* __restrict__ neigh_idx,
    const float* __restrict__ u2e, const short* __restrict__ u2e_bf,
    const float* __restrict__ s, const int* __restrict__ off,
    float* __restrict__ out) {
  const int lane = threadIdx.x & 63, wv = threadIdx.x >> 6;
  const int node = blockIdx.x * 4 + wv;
  const int lo = off[node], hi = off[node + 1];
  float* orow = out + (size_t)node * EMBED;

  if (lo >= hi) {
    const float* src = u2e + (size_t)nodes[node] * EMBED;
    orow[lane] = src[lane];
    orow[lane + 64] = src[lane + 64];
    return;
  }

  float mx = -3.402823466e38f;
  for (int e = lo + lane; e < hi; e += 64) mx = fmaxf(mx, s[e]);
#pragma unroll
  for (int o = 32; o >= 1; o >>= 1) mx = fmaxf(mx, __shfl_xor(mx, o, 64));

  float sum = 0.f;
  for (int e = lo + lane; e < hi; e += 64) sum += expf(s[e] - mx);
#pragma unroll
  for (int o = 32; o >= 1; o >>= 1) sum += __shfl_xor(sum, o, 64);
  const float inv = 1.0f / sum;

  const int eg = lane >> 4, ld = lane & 15;
  f32x4 a0 = (f32x4){0.f, 0.f, 0.f, 0.f};
  f32x4 a1 = (f32x4){0.f, 0.f, 0.f, 0.f};
  f32x4 b0 = (f32x4){0.f, 0.f, 0.f, 0.f};
  f32x4 b1v = (f32x4){0.f, 0.f, 0.f, 0.f};
  int e = lo + eg;
  for (; e + 4 < hi; e += 8) {  // 2 edges per group in flight
    float wA = expf(s[e] - mx) * inv;
    float wB = expf(s[e + 4] - mx) * inv;
    bf16x8 rA = *(const bf16x8*)(u2e_bf + (size_t)neigh_idx[e] * 128 + ld * 8);
    bf16x8 rB = *(const bf16x8*)(u2e_bf + (size_t)neigh_idx[e + 4] * 128 + ld * 8);
#pragma unroll
    for (int c = 0; c < 4; ++c) {
      a0[c] += wA * bf2f(rA[c]);
      a1[c] += wA * bf2f(rA[c + 4]);
      b0[c] += wB * bf2f(rB[c]);
      b1v[c] += wB * bf2f(rB[c + 4]);
    }
  }
  for (; e < hi; e += 4) {
    float w = expf(s[e] - mx) * inv;
    bf16x8 r = *(const bf16x8*)(u2e_bf + (size_t)neigh_idx[e] * 128 + ld * 8);
#pragma unroll
    for (int c = 0; c < 4; ++c) {
      a0[c] += w * bf2f(r[c]);
      a1[c] += w * bf2f(r[c + 4]);
    }
  }
  a0 += b0;
  a1 += b1v;
#pragma unroll
  for (int o = 16; o <= 32; o <<= 1) {
#pragma unroll
    for (int c = 0; c < 4; ++c) {
      a0[c] += __shfl_xor(a0[c], o, 64);
      a1[c] += __shfl_xor(a1[c], o, 64);
    }
  }
  if (eg == 0) {
    // lane ld owns output cols ld*8..ld*8+7 (two f32x4 stores)
    *(f32x4*)(orow + ld * 8) = a0;
    *(f32x4*)(orow + ld * 8 + 4) = a1;
  }
}

// ---------------------------------------------------------------------------
extern "C" void kernel_launch(void* const* d_in, const int* in_sizes, int n_in,
                              void* d_out, int out_size, void* d_ws, size_t ws_size,
                              hipStream_t stream) {
  const int* nodes  = (const int*)d_in[0];
  const int* neigh  = (const int*)d_in[1];
  const int* segs   = (const int*)d_in[2];
  const float* u2e  = (const float*)d_in[3];
  const float* w1   = (const float*)d_in[4];
  const float* b1   = (const float*)d_in[5];
  const float* w2   = (const float*)d_in[6];
  const float* b2   = (const float*)d_in[7];
  const float* w3   = (const float*)d_in[8];
  const float* b3   = (const float*)d_in[9];
  float* out = (float*)d_out;

  char* ws = (char*)d_ws;
  short* w1a    = (short*)(ws);                  // 32 KiB
  short* w1b    = (short*)(ws + 32768);          // 32 KiB
  short* w2bf   = (short*)(ws + 65536);          // 32 KiB
  float* s      = (float*)(ws + 98304);          // 1.28 MB
  int*   off    = (int*)(ws + 1378304);          // 40 KB
  short* P_sw   = (short*)(ws + 1418752);        // 25.6 MB
  short* Q_sw   = (short*)(ws + 27018752);       // 2.56 MB
  short* u2e_bf = (short*)(ws + 29578752);       // 25.6 MB

  hipLaunchKernelGGL(prep_kernel, dim3(1250), dim3(256), 0, stream,
                     segs, w1, w2, off, w1a, w1b, w2bf);
  hipLaunchKernelGGL(row_gemm3_kernel, dim3(PBLK3 + QBLK3), dim3(256), 0, stream,
                     u2e, nodes, w1a, w1b, b1, P_sw, Q_sw, u2e_bf);
  hipLaunchKernelGGL(scores3_kernel, dim3(2500), dim3(256), 0, stream,
                     neigh, segs, P_sw, Q_sw, w2bf, b2, w3, b3, s);
  hipLaunchKernelGGL(agg4_kernel, dim3(2500), dim3(256), 0, stream,
                     nodes, neigh, u2e, u2e_bf, s, off, out);
}